// Round 6
// baseline (379.801 us; speedup 1.0000x reference)
//
#include <hip/hip_runtime.h>

#define N_NODES 100000
#define N_EDGES 3200000
#define D 128

#define K1C    391        // coarse buckets: bucket = dst >> 8 (256 nodes each)
#define CHUNK  6144       // edges per partition block
#define NCHUNK 521        // ceil(N_EDGES / CHUNK)

// ---------------------------------------------------------------------------
// Workspace layout (bytes). Total ~77.3 MB; ws >= 78,000,512 proven round 2.
// ---------------------------------------------------------------------------
static const size_t OFF_SB    = 0;           // S bf16 packed: N*64 uints = 25.6 MB
static const size_t OFF_REC   = 25600000;    // E int2 (coarse-partitioned)
static const size_t OFF_SORT2 = 51200000;    // E int2 (fine-sorted)
static const size_t OFF_OFFS  = 76800000;    // N ints
static const size_t OFF_GHIST = 77200000;
static const size_t OFF_BOFFS = 77204096;
static const size_t OFF_GCUR  = 77208192;

typedef __attribute__((ext_vector_type(8))) short bf16x8;
typedef __attribute__((ext_vector_type(4))) float f32x4;

__device__ __forceinline__ unsigned short f2bf(float f) {
    unsigned u = __float_as_uint(f);
    return (unsigned short)((u + 0x7FFFu + ((u >> 16) & 1u)) >> 16);   // RNE
}

// ---------------------------------------------------------------------------
// S = X @ W via MFMA — verified (absmax matched VALU-bf16 path).
// ---------------------------------------------------------------------------
__global__ __launch_bounds__(256) void gemm_mfma(const float* __restrict__ X,
                                                 const float* __restrict__ W,
                                                 unsigned* __restrict__ Sb) {
    __shared__ __align__(16) union {
        unsigned short wfrag[8][4][64][8];  // [ct][kt][lane][j] = 32 KB
        unsigned       stage[4][32][68];    // [wave][row][dword] = 34 KB
    } u;

    const int t    = threadIdx.x;
    const int lane = t & 63;
    const int wave = t >> 6;
    const int quad = lane >> 4;
    const int li   = lane & 15;
    const int rowBase = blockIdx.x * 128;

    // stage W[k][n] fp32 -> pre-packed bf16 B-fragments
    for (int i = t; i < D * D; i += 256) {
        int k = i >> 7, n = i & 127;
        u.wfrag[n >> 4][k >> 5][((k >> 3) & 3) * 16 + (n & 15)][k & 7] = f2bf(W[i]);
    }
    __syncthreads();

    f32x4 acc[2][8];
#pragma unroll
    for (int rt = 0; rt < 2; ++rt)
#pragma unroll
        for (int ct = 0; ct < 8; ++ct)
            acc[rt][ct] = (f32x4){0.f, 0.f, 0.f, 0.f};

#pragma unroll
    for (int kt = 0; kt < 4; ++kt) {
        bf16x8 a[2];
#pragma unroll
        for (int rt = 0; rt < 2; ++rt) {
            int row = rowBase + wave * 32 + rt * 16 + li;
            if (row >= N_NODES) row = N_NODES - 1;           // clamp; store masked
            const float* xp = X + (size_t)row * D + kt * 32 + quad * 8;
            float4 f0 = ((const float4*)xp)[0];
            float4 f1 = ((const float4*)xp)[1];
            bf16x8 av;
            av[0] = (short)f2bf(f0.x); av[1] = (short)f2bf(f0.y);
            av[2] = (short)f2bf(f0.z); av[3] = (short)f2bf(f0.w);
            av[4] = (short)f2bf(f1.x); av[5] = (short)f2bf(f1.y);
            av[6] = (short)f2bf(f1.z); av[7] = (short)f2bf(f1.w);
            a[rt] = av;
        }
#pragma unroll
        for (int ct = 0; ct < 8; ++ct) {
            bf16x8 b = *(const bf16x8*)&u.wfrag[ct][kt][lane][0];
            acc[0][ct] = __builtin_amdgcn_mfma_f32_16x16x32_bf16(a[0], b, acc[0][ct], 0, 0, 0);
            acc[1][ct] = __builtin_amdgcn_mfma_f32_16x16x32_bf16(a[1], b, acc[1][ct], 0, 0, 0);
        }
    }
    __syncthreads();

    unsigned short* sw = (unsigned short*)&u.stage[wave][0][0];  // 32 x 136 bf16
#pragma unroll
    for (int rt = 0; rt < 2; ++rt)
#pragma unroll
        for (int r = 0; r < 4; ++r) {
            int lrow = rt * 16 + quad * 4 + r;
#pragma unroll
            for (int ct = 0; ct < 8; ++ct)
                sw[lrow * 136 + ct * 16 + li] = f2bf(acc[rt][ct][r]);
        }
    for (int lrow = 0; lrow < 32; ++lrow) {
        int node = rowBase + wave * 32 + lrow;
        if (node < N_NODES)
            Sb[(size_t)node * 64 + lane] = ((unsigned*)sw)[lrow * 68 + lane];
    }
}

// ---------------------------------------------------------------------------
// Coarse histogram over K1C buckets (bucket = dst >> 8)
// ---------------------------------------------------------------------------
__global__ __launch_bounds__(256) void hist_coarse(const int* __restrict__ edst,
                                                   int* __restrict__ ghist) {
    __shared__ int h[K1C];
    for (int i = threadIdx.x; i < K1C; i += 256) h[i] = 0;
    __syncthreads();
    for (int e = blockIdx.x * 256 + threadIdx.x; e < N_EDGES; e += gridDim.x * 256)
        atomicAdd(&h[edst[e] >> 8], 1);
    __syncthreads();
    for (int i = threadIdx.x; i < K1C; i += 256)
        if (h[i]) atomicAdd(&ghist[i], h[i]);
}

__global__ __launch_bounds__(256) void scan_coarse(const int* __restrict__ ghist,
                                                   int* __restrict__ boffs,
                                                   int* __restrict__ gcursor) {
    __shared__ int sc[256];
    const int t = threadIdx.x;
    int v[2]; int s = 0;
#pragma unroll
    for (int j = 0; j < 2; ++j) {
        int idx = t * 2 + j;
        v[j] = (idx < K1C) ? ghist[idx] : 0;
        s += v[j];
    }
    sc[t] = s;
    __syncthreads();
    for (int off = 1; off < 256; off <<= 1) {
        int u = (t >= off) ? sc[t - off] : 0;
        __syncthreads();
        sc[t] += u;
        __syncthreads();
    }
    int run = (t == 0) ? 0 : sc[t - 1];
#pragma unroll
    for (int j = 0; j < 2; ++j) {
        int idx = t * 2 + j;
        if (idx < K1C) { boffs[idx] = run; gcursor[idx] = run; }
        run += v[j];
    }
    if (t == 255) boffs[K1C] = run;
}

// ---------------------------------------------------------------------------
// LDS-staged coarse partition, two-pass-per-block (hist then re-read+scatter).
// rec.x = src | (dst&255)<<17 ; rec.y = val bits.  Int LDS atomics only.
// ---------------------------------------------------------------------------
__global__ __launch_bounds__(512) void partition_edges(
        const int* __restrict__ esrc,
        const int* __restrict__ edst,
        const float* __restrict__ eval,
        int* __restrict__ gcursor,
        int2* __restrict__ rec_out) {
    __shared__ int  hist[K1C];
    __shared__ int  lofs[K1C];
    __shared__ int  gbase[K1C];
    __shared__ int  cur[K1C];
    __shared__ int  sc[512];
    __shared__ int2 staged[CHUNK];
    __shared__ unsigned short bkt[CHUNK];

    const int t   = threadIdx.x;
    const int e0  = blockIdx.x * CHUNK;
    const int cnt = min(CHUNK, N_EDGES - e0);

    for (int i = t; i < K1C; i += 512) hist[i] = 0;
    __syncthreads();

    // pass 1: block-local histogram (edst read is coalesced; re-read below is L2-hot)
    for (int i = t; i < cnt; i += 512)
        atomicAdd(&hist[edst[e0 + i] >> 8], 1);
    __syncthreads();

    // block scan: one bucket per thread (K1C=391 <= 512)
    int hv = (t < K1C) ? hist[t] : 0;
    sc[t] = hv;
    __syncthreads();
    for (int off = 1; off < 512; off <<= 1) {
        int u = (t >= off) ? sc[t - off] : 0;
        __syncthreads();
        sc[t] += u;
        __syncthreads();
    }
    if (t < K1C) {
        int excl = sc[t] - hv;
        lofs[t]  = excl;
        cur[t]   = excl;
        gbase[t] = hv ? atomicAdd(&gcursor[t], hv) : 0;
    }
    __syncthreads();

    // pass 2: re-read edges, scatter into LDS staging (bucket-sorted)
    for (int i = t; i < cnt; i += 512) {
        int e = e0 + i;
        int d = edst[e];
        int b = d >> 8;
        int pos = atomicAdd(&cur[b], 1);
        staged[pos] = make_int2(esrc[e] | ((d & 255) << 17), __float_as_int(eval[e]));
        bkt[pos] = (unsigned short)b;
    }
    __syncthreads();

    // writeout: contiguous per-bucket runs (~126 B each)
    for (int i = t; i < cnt; i += 512) {
        int bb = bkt[i];
        rec_out[gbase[bb] + (i - lofs[bb])] = staged[i];
    }
}

// ---------------------------------------------------------------------------
// Fine sort within each 256-node coarse bucket. Scatter window ~65 KB ->
// L2-resident. Emits per-node segment offsets. One node per thread.
// ---------------------------------------------------------------------------
__global__ __launch_bounds__(256) void fine_sort(
        const int2* __restrict__ rec,
        const int* __restrict__ boffs,
        int* __restrict__ offs,
        int2* __restrict__ sorted2) {
    __shared__ int h[256];
    __shared__ int cur[256];
    __shared__ int sc[256];

    const int c   = blockIdx.x;
    const int t   = threadIdx.x;
    const int beg = boffs[c];
    const int end = boffs[c + 1];

    h[t] = 0;
    __syncthreads();

    for (int i = beg + t; i < end; i += 256)
        atomicAdd(&h[(rec[i].x >> 17) & 255], 1);
    __syncthreads();

    sc[t] = h[t];
    __syncthreads();
    for (int off = 1; off < 128; off <<= 1) {
        int u = (t >= off) ? sc[t - off] : 0;
        __syncthreads();
        sc[t] += u;
        __syncthreads();
    }
    {
        int u = (t >= 128) ? sc[t - 128] : 0;
        __syncthreads();
        sc[t] += u;
        __syncthreads();
    }
    {
        int excl = sc[t] - h[t];
        int node = c * 256 + t;
        if (node < N_NODES) offs[node] = beg + excl;
        cur[t] = beg + excl;
    }
    __syncthreads();

    for (int i = beg + t; i < end; i += 256) {
        int2 q = rec[i];
        int dl = (q.x >> 17) & 255;
        int p = atomicAdd(&cur[dl], 1);
        sorted2[p] = make_int2(q.x & 0x1FFFF, q.y);
    }
}

// ---------------------------------------------------------------------------
// Wave-per-node segmented reduce, quarter-wave record parallelism, with a
// per-batch 64-lane BITONIC SORT BY SRC before gathering. All ~6.2K waves of
// this kernel are co-resident (one cohort); sorted batches make every wave
// sweep src-space in ascending order simultaneously, shrinking the live
// gather window from 25.6 MB (uniform random) to a few MB (L2-resident).
// Pad records are (INT_MAX, val=0): sort STRICTLY after any real src (which
// is <= 99999), so all real records stay in processed slots; the gather
// address clamps with min(key, N_NODES-1) so processed pads read a valid
// S-row and contribute 0 (never 0*NaN from OOB bytes).
// ---------------------------------------------------------------------------
#define FMA8(v, p) {                                                         \
    a0 += (v) * __uint_as_float((p).x << 16);                                \
    a1 += (v) * __uint_as_float((p).x & 0xFFFF0000u);                        \
    a2 += (v) * __uint_as_float((p).y << 16);                                \
    a3 += (v) * __uint_as_float((p).y & 0xFFFF0000u);                        \
    a4 += (v) * __uint_as_float((p).z << 16);                                \
    a5 += (v) * __uint_as_float((p).z & 0xFFFF0000u);                        \
    a6 += (v) * __uint_as_float((p).w << 16);                                \
    a7 += (v) * __uint_as_float((p).w & 0xFFFF0000u);                        \
}

__global__ __launch_bounds__(256) void reduce_segments(
        const unsigned* __restrict__ Sb,
        const int2* __restrict__ sorted,
        const int* __restrict__ offs,
        const float* __restrict__ bias,
        float* __restrict__ out) {
    const int lane = threadIdx.x & 63;
    const int node = (blockIdx.x * 256 + threadIdx.x) >> 6;
    if (node >= N_NODES) return;

    const int qr = lane >> 4;        // which record of the group of 4
    const int ql = lane & 15;        // lane within quarter: feats 8ql..8ql+7

    const int beg = offs[node];
    const int end = (node == N_NODES - 1) ? N_EDGES : offs[node + 1];

    float a0 = 0.f, a1 = 0.f, a2 = 0.f, a3 = 0.f;
    float a4 = 0.f, a5 = 0.f, a6 = 0.f, a7 = 0.f;

    for (int base = beg; base < end; base += 64) {
        const int m = min(64, end - base);
        int2 rec = make_int2(0x7FFFFFFF, 0);         // pad: strict-max key, val 0
        if (base + lane < end) rec = sorted[base + lane];

        // 64-lane bitonic sort ascending by rec.x (src). 21 steps.
#pragma unroll
        for (int k = 2; k <= 64; k <<= 1) {
#pragma unroll
            for (int j = k >> 1; j > 0; j >>= 1) {
                int ox = __shfl_xor(rec.x, j);
                int oy = __shfl_xor(rec.y, j);
                bool dirUp  = ((lane & k) == 0);
                bool lower  = ((lane & j) == 0);
                bool keepSm = (dirUp == lower);
                bool take   = keepSm ? (ox < rec.x) : (ox > rec.x);
                rec.x = take ? ox : rec.x;
                rec.y = take ? oy : rec.y;
            }
        }

        const int ng = (m + 3) >> 2;         // groups of 4 records

        int g = 0;
        for (; g + 4 <= ng; g += 4) {
            int i0 = 4 * (g + 0) + qr, i1 = 4 * (g + 1) + qr;
            int i2 = 4 * (g + 2) + qr, i3 = 4 * (g + 3) + qr;
            int s0 = min(__shfl(rec.x, i0), N_NODES - 1);
            int s1 = min(__shfl(rec.x, i1), N_NODES - 1);
            int s2 = min(__shfl(rec.x, i2), N_NODES - 1);
            int s3 = min(__shfl(rec.x, i3), N_NODES - 1);
            float v0 = __int_as_float(__shfl(rec.y, i0));
            float v1 = __int_as_float(__shfl(rec.y, i1));
            float v2 = __int_as_float(__shfl(rec.y, i2));
            float v3 = __int_as_float(__shfl(rec.y, i3));
            uint4 p0 = ((const uint4*)(Sb + (size_t)s0 * 64))[ql];
            uint4 p1 = ((const uint4*)(Sb + (size_t)s1 * 64))[ql];
            uint4 p2 = ((const uint4*)(Sb + (size_t)s2 * 64))[ql];
            uint4 p3 = ((const uint4*)(Sb + (size_t)s3 * 64))[ql];
            FMA8(v0, p0);
            FMA8(v1, p1);
            FMA8(v2, p2);
            FMA8(v3, p3);
        }
        for (; g < ng; ++g) {
            int i0 = 4 * g + qr;
            int s0 = min(__shfl(rec.x, i0), N_NODES - 1);
            float v0 = __int_as_float(__shfl(rec.y, i0));
            uint4 p0 = ((const uint4*)(Sb + (size_t)s0 * 64))[ql];
            FMA8(v0, p0);
        }
    }

    // combine the four quarters (feats 8ql..8ql+7 live in lanes ql, ql+16,
    // ql+32, ql+48)
    a0 += __shfl(a0, lane ^ 16); a1 += __shfl(a1, lane ^ 16);
    a2 += __shfl(a2, lane ^ 16); a3 += __shfl(a3, lane ^ 16);
    a4 += __shfl(a4, lane ^ 16); a5 += __shfl(a5, lane ^ 16);
    a6 += __shfl(a6, lane ^ 16); a7 += __shfl(a7, lane ^ 16);
    a0 += __shfl(a0, lane ^ 32); a1 += __shfl(a1, lane ^ 32);
    a2 += __shfl(a2, lane ^ 32); a3 += __shfl(a3, lane ^ 32);
    a4 += __shfl(a4, lane ^ 32); a5 += __shfl(a5, lane ^ 32);
    a6 += __shfl(a6, lane ^ 32); a7 += __shfl(a7, lane ^ 32);

    if (qr == 0) {
        float4 b0 = ((const float4*)bias)[2 * ql];
        float4 b1 = ((const float4*)bias)[2 * ql + 1];
        float4 r0 = make_float4(a0 + b0.x, a1 + b0.y, a2 + b0.z, a3 + b0.w);
        float4 r1 = make_float4(a4 + b1.x, a5 + b1.y, a6 + b1.z, a7 + b1.w);
        ((float4*)(out + (size_t)node * D))[2 * ql]     = r0;
        ((float4*)(out + (size_t)node * D))[2 * ql + 1] = r1;
    }
}

extern "C" void kernel_launch(void* const* d_in, const int* in_sizes, int n_in,
                              void* d_out, int out_size, void* d_ws, size_t ws_size,
                              hipStream_t stream) {
    const float* X    = (const float*)d_in[0];
    const int*   esrc = (const int*)  d_in[1];
    const int*   edst = (const int*)  d_in[2];
    const float* eval = (const float*)d_in[3];
    const float* W    = (const float*)d_in[4];
    const float* bias = (const float*)d_in[5];
    float* out = (float*)d_out;

    char* ws = (char*)d_ws;
    unsigned* SbU   = (unsigned*)(ws + OFF_SB);
    int2*     recs  = (int2*)    (ws + OFF_REC);
    int2*     srt2  = (int2*)    (ws + OFF_SORT2);
    int*      offs  = (int*)     (ws + OFF_OFFS);
    int*      ghist = (int*)     (ws + OFF_GHIST);
    int*      boffs = (int*)     (ws + OFF_BOFFS);
    int*      gcur  = (int*)     (ws + OFF_GCUR);

    // S = X @ W (bf16, MFMA)
    gemm_mfma<<<782, 256, 0, stream>>>(X, W, SbU);

    // Two-level counting sort of edges by dst (all scatters L2-resident)
    hipMemsetAsync(ghist, 0, K1C * 4, stream);
    hist_coarse<<<256, 256, 0, stream>>>(edst, ghist);
    scan_coarse<<<1, 256, 0, stream>>>(ghist, boffs, gcur);
    partition_edges<<<NCHUNK, 512, 0, stream>>>(esrc, edst, eval, gcur, recs);
    fine_sort<<<K1C, 256, 0, stream>>>(recs, boffs, offs, srt2);

    // Segmented reduce: out[n] = bias + sum val * S[src]
    reduce_segments<<<(N_NODES + 3) / 4, 256, 0, stream>>>(
        SbU, srt2, offs, bias, out);
}